// Round 22
// baseline (73.061 us; speedup 1.0000x reference)
//
#include <hip/hip_runtime.h>
#include <hip/hip_bf16.h>
#include <math.h>

#define B_  4
#define T_  4096
#define C_  1024
#define HS_ 128

using bf16x8 = __attribute__((ext_vector_type(8))) __bf16;
using bf16x4 = __attribute__((ext_vector_type(4))) __bf16;
using f32x4  = __attribute__((ext_vector_type(4))) float;

#define MFMA(a, b, c) __builtin_amdgcn_mfma_f32_16x16x32_bf16(a, b, c, 0, 0, 0)

typedef __attribute__((address_space(1))) const float gfloat;
typedef __attribute__((address_space(3))) float lfloat;

// fast exp2 via v_exp_f32; trailing s_nop covers the 1-wait-state trans hazard
__device__ inline float fexp2(float x) {
  float r;
  asm volatile("v_exp_f32 %0, %1\n\ts_nop 0" : "=v"(r) : "v"(x));
  return r;
}

// ---------------------------------------------------------------------------
// Fragment-tiled layouts (see R8/R9): loads matching MFMA fragment order are
// single contiguous 1KB blocks -> no request amplification.
//   Qf[b*128+t][j=rt*4+cs][l][e] = Q[t*32 + rt*16 + (l&15)][cs*32+(l>>4)*8+e]
//   Kf[b*128+t][j=2cs+hi ][l][e] = K[t*32 + kp(l&15)+4hi   ][cs*32+(l>>4)*8+e]
//   Vf[b*128+t][j=db     ][l][e] = V[t*32 + (l>>4)*8+e     ][db*16 + (l&15)]
//   Wf[u*32+t][l][e]             = W_m[col=(u&7)*16+(l&15)][k=t*32+(l>>4)*8+e]
// (kp(c)=((c&12)<<1)|(c&3); u=0..23, m=u>>3, t=K-step).
// ---------------------------------------------------------------------------

// ---------------------------------------------------------------------------
// Kernel 1: W fp32 [1024][128] -> Wf bf16 fragment-tiled (see above) via LDS
// transpose. m=0: Wq scaled by 1/sqrt(128)*log2(e) (exp2-domain softmax).
// ---------------------------------------------------------------------------
__global__ __launch_bounds__(256) void prep_w_kernel(
    const float* __restrict__ Wk, const float* __restrict__ Wq,
    const float* __restrict__ Wv, __bf16* __restrict__ Wf) {
  const int m  = blockIdx.x >> 4;        // 0..2
  const int k0 = (blockIdx.x & 15) * 64; // k-slab base
  const float* W = (m == 0) ? Wq : ((m == 1) ? Wk : Wv);
  const float scale = (m == 0) ? (0.08838834764831845f * 1.4426950408889634f) : 1.0f;
  __shared__ __bf16 tile[128][72];       // [n][k-within-slab], padded
  const int t = threadIdx.x;
#pragma unroll
  for (int p = 0; p < 8; ++p) {
    int e  = p * 1024 + t * 4;
    int r  = e >> 7;                     // 0..63
    int cc = e & 127;
    float4 w = *reinterpret_cast<const float4*>(&W[(size_t)(k0 + r) * HS_ + cc]);
    tile[cc + 0][r] = (__bf16)(w.x * scale);
    tile[cc + 1][r] = (__bf16)(w.y * scale);
    tile[cc + 2][r] = (__bf16)(w.z * scale);
    tile[cc + 3][r] = (__bf16)(w.w * scale);
  }
  __syncthreads();
#pragma unroll
  for (int p = 0; p < 4; ++p) {
    int e  = p * 2048 + t * 8;
    int n  = e >> 6;                     // 0..127 (col within matrix m)
    int kk = e & 63;                     // k within slab (multiple of 8)
    bf16x8 v;
#pragma unroll
    for (int jj = 0; jj < 8; ++jj) v[jj] = tile[n][kk + jj];
    // fragment-tiled address: u = m*8+(n>>4); lane = g2*16+(n&15)
    int u  = m * 8 + (n >> 4);
    int ts = (k0 + kk) >> 5;
    int g2 = (kk >> 3) & 3;
    *reinterpret_cast<bf16x8*>(
        &Wf[((size_t)(u * 32 + ts) * 64 + g2 * 16 + (n & 15)) * 8]) = v;
  }
}

__device__ inline bf16x8 cvt8p(float4 u, float4 v) {
  bf16x8 r;
  r[0] = (__bf16)u.x; r[1] = (__bf16)u.y; r[2] = (__bf16)u.z; r[3] = (__bf16)u.w;
  r[4] = (__bf16)v.x; r[5] = (__bf16)v.y; r[6] = (__bf16)v.z; r[7] = (__bf16)v.w;
  return r;
}

// ---------------------------------------------------------------------------
// Kernel 2: projections. R20 post-mortem: 32 waves/CU REGRESSED (65us) —
// occupancy was never the binder; W arithmetic intensity is. Halving rows
// per block doubled W L2 traffic and time followed. All R16-R18 variants
// shared the 32-row tile: 393MB W reads, 3 MFMA per wave-barrier-iter.
// R21: m97-class tile. Block = 128 rows x 128 cols (= one matrix m),
// grid 384 (128 rowtiles x 3), 4 waves x 32 rows, acc[8][2], BK=32:
//  * per wave-iter: 16 MFMA / 12 ds_read_b128 (5x density of R18);
//  * W traffic 393 -> 98 MB (4x reuse);
//  * x tile 128x32 fp32 = 16KB staged with the proven chunk^(row&7)
//    both-sides swizzle; W tile 8KB staged from fragment-tiled Wf (each
//    (u,t) is 1KB contiguous global; LDS read nt*1024+l*16 = linear,
//    conflict-free); both via global_load_lds width 16;
//  * double-buffered 48KB LDS, classic stage->compute->drain loop.
// Epilogue: R13-verified fragment-tiled stores, m fixed, tile=rowtile*4+wid.
// ---------------------------------------------------------------------------
__global__ __launch_bounds__(256) void proj_kernel(
    const float* __restrict__ x, const __bf16* __restrict__ Wf,
    __bf16* __restrict__ Qf, __bf16* __restrict__ Kf, __bf16* __restrict__ Vf) {
  __shared__ __align__(16) char lds[49152];   // 2 x (16KB x + 8KB W)
  const int tid = threadIdx.x;
  const int wid = tid >> 6;      // 0..3
  const int l   = tid & 63;
  const int c   = l & 15;        // A-row / B-col slot
  const int g   = l >> 4;        // k-group
  const int m       = blockIdx.x % 3;     // matrix (0=Q,1=K,2=V)
  const int rowtile = blockIdx.x / 3;     // 0..127
  const int rbase   = rowtile * 128;

  f32x4 acc[8][2];               // [nt][rt]
#pragma unroll
  for (int i = 0; i < 8; ++i) { acc[i][0] = 0.f; acc[i][1] = 0.f; }

  // ---- x staging: 4 ops x 256 thr x 16B. id = op*256+tid; row = id>>3,
  // ch = id&7 (linear dest chunk); source chunk = ch ^ (row&7).
  const float* xsrc[4];
#pragma unroll
  for (int op = 0; op < 4; ++op) {
    int id  = op * 256 + tid;
    int row = id >> 3;
    int ch  = id & 7;
    xsrc[op] = x + (size_t)(rbase + row) * C_ + ((ch ^ (row & 7)) << 2);
  }
  // ---- W staging: 2 ops x 256 thr x 16B from the fragment-tiled stream.
  // id = i*256+tid; ul = id>>6 (unit within m), ln = id&63.
  const __bf16* wsrc[2];
#pragma unroll
  for (int i = 0; i < 2; ++i) {
    int id = i * 256 + tid;
    int ul = id >> 6;
    int ln = id & 63;
    wsrc[i] = Wf + (size_t)((m * 8 + ul) * 32) * 512 + ln * 8;
  }

  auto stage = [&](int t, int bo) {
#pragma unroll
    for (int op = 0; op < 4; ++op)
      __builtin_amdgcn_global_load_lds((gfloat*)(xsrc[op] + t * 32),
          (lfloat*)(lds + bo + (op * 256 + tid) * 16), 16, 0, 0);
#pragma unroll
    for (int i = 0; i < 2; ++i)
      __builtin_amdgcn_global_load_lds((gfloat*)(wsrc[i] + t * 512),
          (lfloat*)(lds + bo + 16384 + (i * 256 + tid) * 16), 16, 0, 0);
  };

  // ---- compute-side LDS offsets ----
  int woffs[8];
#pragma unroll
  for (int nt = 0; nt < 8; ++nt)
    woffs[nt] = 16384 + nt * 1024 + l * 16;     // linear, conflict-free
  int xoffs[2][2];
#pragma unroll
  for (int rt = 0; rt < 2; ++rt) {
    int row = wid * 32 + rt * 16 + c;
#pragma unroll
    for (int j = 0; j < 2; ++j)
      xoffs[rt][j] = row * 128 + ((((g << 1) | j) ^ (row & 7)) << 4);
  }

  stage(0, 0);
  asm volatile("s_waitcnt vmcnt(0)" ::: "memory");
  __syncthreads();

  for (int t = 0; t < 32; ++t) {
    const int bo = (t & 1) * 24576;
    if (t + 1 < 32) stage(t + 1, bo ^ 24576);

    bf16x8 wf[8];
#pragma unroll
    for (int nt = 0; nt < 8; ++nt)
      wf[nt] = *reinterpret_cast<const bf16x8*>(lds + bo + woffs[nt]);
#pragma unroll
    for (int rt = 0; rt < 2; ++rt) {
      float4 lo = *reinterpret_cast<const float4*>(lds + bo + xoffs[rt][0]);
      float4 hi = *reinterpret_cast<const float4*>(lds + bo + xoffs[rt][1]);
      bf16x8 a = cvt8p(lo, hi);
#pragma unroll
      for (int nt = 0; nt < 8; ++nt) acc[nt][rt] = MFMA(a, wf[nt], acc[nt][rt]);
    }

    asm volatile("s_waitcnt vmcnt(0)" ::: "memory");
    __syncthreads();
  }

  // ---- epilogue: fragment-tiled stores (tile = rowtile*4 + wid, m fixed) ----
  const size_t tile = (size_t)rowtile * 4 + wid;
#pragma unroll
  for (int nt = 0; nt < 8; ++nt) {
    const int gprime = ((nt & 1) << 1) + (c >> 3);  // col-group (l'>>4)
    const int e = c & 7;
    if (m == 0) {
      // j = rt*4 + (nt>>1); l' = gprime*16 + (4g+rr)
#pragma unroll
      for (int rt = 0; rt < 2; ++rt)
#pragma unroll
        for (int rr = 0; rr < 4; ++rr)
          Qf[(tile * 8 + rt * 4 + (nt >> 1)) * 512 +
             (gprime * 16 + 4 * g + rr) * 8 + e] = (__bf16)acc[nt][rt][rr];
    } else if (m == 1) {
      // rho = rt*16+4g+rr: hi = g&1; c'' = ((2rt+(g>>1))<<2)|rr
#pragma unroll
      for (int rt = 0; rt < 2; ++rt)
#pragma unroll
        for (int rr = 0; rr < 4; ++rr)
          Kf[(tile * 8 + 2 * (nt >> 1) + (g & 1)) * 512 +
             (gprime * 16 + (((2 * rt + (g >> 1)) << 2) | rr)) * 8 + e] =
              (__bf16)acc[nt][rt][rr];
    } else {
      // j = nt; l' = (2rt+(g>>1))*16 + c; e = 4(g&1)+rr (contiguous in rr)
#pragma unroll
      for (int rt = 0; rt < 2; ++rt) {
        bf16x4 v4;
#pragma unroll
        for (int rr = 0; rr < 4; ++rr) v4[rr] = (__bf16)acc[nt][rt][rr];
        *reinterpret_cast<bf16x4*>(
            Vf + (tile * 8 + nt) * 512 +
            ((2 * rt + (g >> 1)) * 16 + c) * 8 + 4 * (g & 1)) = v4;
      }
    }
  }
}

// ---------------------------------------------------------------------------
// Kernel 3: causal flash attention. 4 waves/block; each wave owns the FULL
// 32 q-rows (acc[2][8]) with 4-way kt split. All Q/K/V global loads are
// fragment-tiled: base + chunk*512 + l*8 -> perfectly coalesced 1KB blocks.
// S^T = mfma(K_perm, Q^T); P per-lane IS the PV B-fragment. Per-lane softmax
// gate (__all), lrun per-lane partial reduced once at wave end. exp2 domain.
// ---------------------------------------------------------------------------
__global__ __launch_bounds__(256, 2) void attn_kernel(
    const __bf16* __restrict__ Qf, const __bf16* __restrict__ Kf,
    const __bf16* __restrict__ Vf, float* __restrict__ out) {
  __shared__ float sm[4][32];
  __shared__ float sl[4][32];
  __shared__ float bufA[32][132];
  __shared__ float bufB[32][132];

  const int tid = threadIdx.x;
  const int wid = tid >> 6;
  const int l   = tid & 63;
  const int c   = l & 15;
  const int g   = l >> 4;
  const int bid = blockIdx.x;
  const int b   = (bid & 7) >> 1;                    // XCD-affine batch
  const int j   = ((bid >> 3) << 1) | (bid & 1);     // 0..127
  const int qt  = (j < 64) ? (127 - j) : (j - 64);   // big tiles dispatched first
  const int qb  = qt * 32;

  bf16x8 qf[2][4];
  {
    const __bf16* Qt = Qf + (size_t)(b * 128 + qt) * 4096 + l * 8;
#pragma unroll
    for (int rt = 0; rt < 2; ++rt)
#pragma unroll
      for (int cs = 0; cs < 4; ++cs)
        qf[rt][cs] = *reinterpret_cast<const bf16x8*>(Qt + (rt * 4 + cs) * 512);
  }

  f32x4 acc[2][8];
#pragma unroll
  for (int i = 0; i < 2; ++i)
#pragma unroll
    for (int d = 0; d < 8; ++d) acc[i][d] = 0.f;
  float mrun[2] = {-INFINITY, -INFINITY};
  float lrun[2] = {0.f, 0.f};   // PER-LANE partial sums (reduced at wave end)

  if (wid <= qt) {
    const __bf16* Kb8 = Kf + (size_t)b * 128 * 4096 + l * 8;
    const __bf16* Vb8 = Vf + (size_t)b * 128 * 4096 + l * 8;
    bf16x8 kreg[8];
    auto kload = [&](int kt) {
      const __bf16* kb = Kb8 + (size_t)kt * 4096;
#pragma unroll
      for (int jj = 0; jj < 8; ++jj)
        kreg[jj] = *reinterpret_cast<const bf16x8*>(kb + jj * 512);
    };
    kload(wid);

    for (int kt = wid; kt <= qt; kt += 4) {
      f32x4 s00 = 0.f, s01 = 0.f, s10 = 0.f, s11 = 0.f;
      __builtin_amdgcn_s_setprio(1);
#pragma unroll
      for (int cs = 0; cs < 4; ++cs) {
        s00 = MFMA(kreg[2 * cs], qf[0][cs], s00);
        s01 = MFMA(kreg[2 * cs + 1], qf[0][cs], s01);
        s10 = MFMA(kreg[2 * cs], qf[1][cs], s10);
        s11 = MFMA(kreg[2 * cs + 1], qf[1][cs], s11);
      }
      __builtin_amdgcn_s_setprio(0);

      bf16x8 vf[8];
      {
        const __bf16* vb = Vb8 + (size_t)kt * 4096;
#pragma unroll
        for (int db = 0; db < 8; ++db)
          vf[db] = *reinterpret_cast<const bf16x8*>(vb + db * 512);
      }

      if (kt + 4 <= qt) kload(kt + 4);        // prefetch next K tile

      const bool maskt = (kt == qt);           // only the diagonal tile
      bf16x8 pb[2];
#pragma unroll
      for (int rt = 0; rt < 2; ++rt) {
        float p[8];
        const f32x4 sa = rt ? s10 : s00;
        const f32x4 sb = rt ? s11 : s01;
#pragma unroll
        for (int rr = 0; rr < 4; ++rr) { p[rr] = sa[rr]; p[4 + rr] = sb[rr]; }
        if (maskt) {
          const int lim = rt * 16 + c;
#pragma unroll
          for (int jj = 0; jj < 8; ++jj)
            if (8 * g + jj > lim) p[jj] = -INFINITY;
        }
        // per-lane max only (no cross-lane on the common path)
        float t0 = fmaxf(fmaxf(p[0], p[1]), p[2]);
        float t1 = fmaxf(fmaxf(p[3], p[4]), p[5]);
        float t2 = fmaxf(fmaxf(p[6], p[7]), t0);
        float tmax = fmaxf(t1, t2);

        if (!__all(tmax <= mrun[rt] + 11.5415603f)) {   // rare: defer-max fired
          float cmax = fmaxf(tmax, __shfl_xor(tmax, 16));
          cmax = fmaxf(cmax, __shfl_xor(cmax, 32));     // column max (over g)
          float mnew = fmaxf(mrun[rt], cmax);
          float al   = fexp2(mrun[rt] - mnew);
          mrun[rt] = mnew;
          lrun[rt] *= al;
#pragma unroll
          for (int db = 0; db < 8; ++db) acc[rt][db] *= al;
        }
        const float mc = mrun[rt];
#pragma unroll
        for (int jj = 0; jj < 8; ++jj) p[jj] = fexp2(p[jj] - mc);
        lrun[rt] += ((p[0] + p[1]) + (p[2] + p[3])) + ((p[4] + p[5]) + (p[6] + p[7]));
#pragma unroll
        for (int jj = 0; jj < 8; ++jj) pb[rt][jj] = (__bf16)p[jj];
      }

      __builtin_amdgcn_s_setprio(1);
#pragma unroll
      for (int db = 0; db < 8; ++db) {
        acc[0][db] = MFMA(vf[db], pb[0], acc[0][db]);
        acc[1][db] = MFMA(vf[db], pb[1], acc[1][db]);
      }
      __builtin_amdgcn_s_setprio(0);
    }
  }

  // wave-end: reduce per-lane l partials across the 4 g-lanes of each column
#pragma unroll
  for (int rt = 0; rt < 2; ++rt) {
    lrun[rt] += __shfl_xor(lrun[rt], 16);
    lrun[rt] += __shfl_xor(lrun[rt], 32);
  }

  // ---- combine the 4 waves' partial (m, l, O) ----
  if (g == 0) {
    sm[wid][c] = mrun[0]; sm[wid][16 + c] = mrun[1];
    sl[wid][c] = lrun[0]; sl[wid][16 + c] = lrun[1];
  }
  __syncthreads();

  float linv[2];
#pragma unroll
  for (int rt = 0; rt < 2; ++rt) {
    const int q = rt * 16 + c;
    float ms = fmaxf(fmaxf(sm[0][q], sm[1][q]), fmaxf(sm[2][q], sm[3][q]));
    float ls = fexp2(sm[0][q] - ms) * sl[0][q] + fexp2(sm[1][q] - ms) * sl[1][q]
             + fexp2(sm[2][q] - ms) * sl[2][q] + fexp2(sm[3][q] - ms) * sl[3][q];
    float al = fexp2(mrun[rt] - ms);
#pragma unroll
    for (int db = 0; db < 8; ++db) acc[rt][db] *= al;
    linv[rt] = 1.0f / ls;
  }

  auto store_buf = [&](float(*buf)[132]) {
#pragma unroll
    for (int rt = 0; rt < 2; ++rt)
#pragma unroll
      for (int db = 0; db < 8; ++db)
        *reinterpret_cast<f32x4*>(&buf[rt * 16 + c][db * 16 + 4 * g]) = acc[rt][db];
  };
  auto add_buf = [&](float(*buf)[132]) {
#pragma unroll
    for (int rt = 0; rt < 2; ++rt)
#pragma unroll
      for (int db = 0; db < 8; ++db)
        acc[rt][db] += *reinterpret_cast<const f32x4*>(&buf[rt * 16 + c][db * 16 + 4 * g]);
  };

  if (wid == 2) store_buf(bufA);
  if (wid == 3) store_buf(bufB);
  __syncthreads();
  if (wid == 0) add_buf(bufA);
  if (wid == 1) add_buf(bufB);
  __syncthreads();
  if (wid == 1) store_buf(bufA);
  __syncthreads();
  if (wid == 0) {
    add_buf(bufA);
    float* op = out + ((size_t)b * T_ + qb) * HS_;
#pragma unroll
    for (int rt = 0; rt < 2; ++rt)
#pragma unroll
      for (int db = 0; db < 8; ++db) {
        f32x4 v = acc[rt][db] * linv[rt];
        *reinterpret_cast<f32x4*>(op + (size_t)(rt * 16 + c) * HS_ + db * 16 + 4 * g) = v;
      }
  }
}

// ---------------------------------------------------------------------------
extern "C" void kernel_launch(void* const* d_in, const int* in_sizes, int n_in,
                              void* d_out, int out_size, void* d_ws, size_t ws_size,
                              hipStream_t stream) {
  const float* x  = (const float*)d_in[0];
  const float* Wk = (const float*)d_in[1];
  const float* Wq = (const float*)d_in[2];
  const float* Wv = (const float*)d_in[3];
  float* out = (float*)d_out;

  char* ws = (char*)d_ws;
  __bf16* Wf = (__bf16*)ws;                              // 768 KiB (fragment-tiled)
  __bf16* Qf = (__bf16*)(ws + 786432);                   // 4 MiB (fragment-tiled)
  __bf16* Kf = (__bf16*)(ws + 786432 + 4194304);         // 4 MiB (fragment-tiled)
  __bf16* Vf = (__bf16*)(ws + 786432 + 8388608);         // 4 MiB (fragment-tiled)

  prep_w_kernel<<<48, 256, 0, stream>>>(Wk, Wq, Wv, Wf);
  proj_kernel<<<384, 256, 0, stream>>>(x, Wf, Qf, Kf, Vf);
  attn_kernel<<<512, 256, 0, stream>>>(Qf, Kf, Vf, out);
}

// Round 23
// 60.659 us; speedup vs baseline: 1.2044x; 1.2044x over previous
//
#include <hip/hip_runtime.h>
#include <hip/hip_bf16.h>
#include <math.h>

#define B_  4
#define T_  4096
#define C_  1024
#define HS_ 128

using bf16x8 = __attribute__((ext_vector_type(8))) __bf16;
using bf16x4 = __attribute__((ext_vector_type(4))) __bf16;
using f32x4  = __attribute__((ext_vector_type(4))) float;

#define MFMA(a, b, c) __builtin_amdgcn_mfma_f32_16x16x32_bf16(a, b, c, 0, 0, 0)

typedef __attribute__((address_space(1))) const float gfloat;
typedef __attribute__((address_space(3))) float lfloat;

// fast exp2 via v_exp_f32; trailing s_nop covers the 1-wait-state trans hazard
__device__ inline float fexp2(float x) {
  float r;
  asm volatile("v_exp_f32 %0, %1\n\ts_nop 0" : "=v"(r) : "v"(x));
  return r;
}

// ---------------------------------------------------------------------------
// Fragment-tiled layouts (see R8/R9): loads matching MFMA fragment order are
// single contiguous 1KB blocks -> no request amplification.
//   Qf[b*128+t][j=rt*4+cs][l][e] = Q[t*32 + rt*16 + (l&15)][cs*32+(l>>4)*8+e]
//   Kf[b*128+t][j=2cs+hi ][l][e] = K[t*32 + kp(l&15)+4hi   ][cs*32+(l>>4)*8+e]
//   Vf[b*128+t][j=db     ][l][e] = V[t*32 + (l>>4)*8+e     ][db*16 + (l&15)]
//   Wf[u*32+t][l][e]             = W_m[col=(u&7)*16+(l&15)][k=t*32+(l>>4)*8+e]
// (kp(c)=((c&12)<<1)|(c&3); u=0..23, m=u>>3, t=K-step).
// ---------------------------------------------------------------------------

// ---------------------------------------------------------------------------
// Kernel 1: W fp32 [1024][128] -> Wf bf16 fragment-tiled (see above) via LDS
// transpose. m=0: Wq scaled by 1/sqrt(128)*log2(e) (exp2-domain softmax).
// ---------------------------------------------------------------------------
__global__ __launch_bounds__(256) void prep_w_kernel(
    const float* __restrict__ Wk, const float* __restrict__ Wq,
    const float* __restrict__ Wv, __bf16* __restrict__ Wf) {
  const int m  = blockIdx.x >> 4;        // 0..2
  const int k0 = (blockIdx.x & 15) * 64; // k-slab base
  const float* W = (m == 0) ? Wq : ((m == 1) ? Wk : Wv);
  const float scale = (m == 0) ? (0.08838834764831845f * 1.4426950408889634f) : 1.0f;
  __shared__ __bf16 tile[128][72];       // [n][k-within-slab], padded
  const int t = threadIdx.x;
#pragma unroll
  for (int p = 0; p < 8; ++p) {
    int e  = p * 1024 + t * 4;
    int r  = e >> 7;                     // 0..63
    int cc = e & 127;
    float4 w = *reinterpret_cast<const float4*>(&W[(size_t)(k0 + r) * HS_ + cc]);
    tile[cc + 0][r] = (__bf16)(w.x * scale);
    tile[cc + 1][r] = (__bf16)(w.y * scale);
    tile[cc + 2][r] = (__bf16)(w.z * scale);
    tile[cc + 3][r] = (__bf16)(w.w * scale);
  }
  __syncthreads();
#pragma unroll
  for (int p = 0; p < 4; ++p) {
    int e  = p * 2048 + t * 8;
    int n  = e >> 6;                     // 0..127 (col within matrix m)
    int kk = e & 63;                     // k within slab (multiple of 8)
    bf16x8 v;
#pragma unroll
    for (int jj = 0; jj < 8; ++jj) v[jj] = tile[n][kk + jj];
    // fragment-tiled address: u = m*8+(n>>4); lane = g2*16+(n&15)
    int u  = m * 8 + (n >> 4);
    int ts = (k0 + kk) >> 5;
    int g2 = (kk >> 3) & 3;
    *reinterpret_cast<bf16x8*>(
        &Wf[((size_t)(u * 32 + ts) * 64 + g2 * 16 + (n & 15)) * 8]) = v;
  }
}

__device__ inline bf16x8 cvt8p(float4 u, float4 v) {
  bf16x8 r;
  r[0] = (__bf16)u.x; r[1] = (__bf16)u.y; r[2] = (__bf16)u.z; r[3] = (__bf16)u.w;
  r[4] = (__bf16)v.x; r[5] = (__bf16)v.y; r[6] = (__bf16)v.z; r[7] = (__bf16)v.w;
  return r;
}

// ---------------------------------------------------------------------------
// Kernel 2: projections. R22 post-mortem: big tile tripled x HBM traffic
// (%3 matrix split) and dropped occupancy to 6 waves/CU -> 3900cyc/iter.
// Session data now separates cleanly: per-barrier-iteration cost ~1800cyc
// at 16 waves/CU, nearly invariant to work per iteration. R23 lever:
// HALVE THE ITERATION COUNT (BK=64) on the best-known skeleton (R18).
//  * same 512 blocks x 8 waves x 32 rows; W direct global->reg from Wf;
//    raw s_barrier; x triple-buffered;
//  * x tile 8KB (32 rows x 64 floats), 4x4B DMA ops/thread, both-sides
//    chunk^(row&15) swizzle (16 chunks/row now; read = 2 lanes/bank);
//  * per iter: wf0,wf1 (6 bf16x8) issued BEFORE xstage(t+2) so MFMA's
//    implicit waits (vmcnt~7 for s=0, ~4 for s=1) transitively drain
//    x(t+1) while x(t+2) stays in flight across the barrier;
//  * 16 iterations, 12 MFMA/wave/iter (2 K-steps per barrier).
// Epilogue: R18's verified fragment-tiled stores (tile = blockIdx.x).
// ---------------------------------------------------------------------------
__global__ __launch_bounds__(512) void proj_kernel(
    const float* __restrict__ x, const __bf16* __restrict__ Wf,
    __bf16* __restrict__ Qf, __bf16* __restrict__ Kf, __bf16* __restrict__ Vf) {
  __shared__ __align__(16) char lds[24576];   // 3 x 8KB x tiles
  const int tid = threadIdx.x;
  const int wid = tid >> 6;      // 0..7
  const int l   = tid & 63;
  const int c   = l & 15;        // A-row / B-col slot
  const int g   = l >> 4;        // k-group
  const int rbase = blockIdx.x * 32;

  f32x4 acc[3][2];
#pragma unroll
  for (int i = 0; i < 3; ++i) { acc[i][0] = 0.f; acc[i][1] = 0.f; }

  // ---- x staging: 4 ops x 512 threads x 4B = 8KB tile (32 rows x 64 fl).
  // id = op*512+tid; row = id>>6, w = id&63; dest byte = id*4 (linear);
  // source float = (rbase+row)*C + ((w>>2)^(row&15))*4 + (w&3).
  // Image: LDS[row][chunk'] = x[row][chunk' ^ (row&15)] (16B chunks).
  const float* xsrc[4];
#pragma unroll
  for (int op = 0; op < 4; ++op) {
    int id  = op * 512 + tid;
    int row = id >> 6;
    int w   = id & 63;
    xsrc[op] = x + (size_t)(rbase + row) * C_ +
               ((((w >> 2) ^ (row & 15)) << 2) | (w & 3));
  }
  auto xstage = [&](int t, int xbo) {
#pragma unroll
    for (int op = 0; op < 4; ++op)
      __builtin_amdgcn_global_load_lds((gfloat*)(xsrc[op] + t * 64),
          (lfloat*)(lds + xbo + (op * 512 + tid) * 4), 4, 0, 0);
  };

  // ---- W: direct fragment-tiled global stream ----
  const __bf16* wb = Wf + (size_t)(wid * 3) * 16384 + l * 8; // unit i: +i*16384, t-step: +512

  // ---- x read offsets: row = rt*16+c, k-step s, half j:
  // chunk = s*8 + g*2 + j; byte = row*256 + ((chunk ^ (row&15))<<4).
  int xoffs[2][2][2];
#pragma unroll
  for (int rt = 0; rt < 2; ++rt) {
    int row = rt * 16 + c;
#pragma unroll
    for (int s = 0; s < 2; ++s)
#pragma unroll
      for (int j = 0; j < 2; ++j)
        xoffs[rt][s][j] = row * 256 + ((((s * 8 + (g << 1)) | j) ^ (row & 15)) << 4);
  }

  // ---- prologue: x(0), x(1) in flight; x(0) drained ----
  xstage(0, 0);
  xstage(1, 8192);
  asm volatile("s_waitcnt vmcnt(4)" ::: "memory");
  __builtin_amdgcn_s_barrier();

  int xb_cur = 0, xb_nxt = 8192, xb_fut = 16384;
  for (int t = 0; t < 16; ++t) {
    // W(2t), W(2t+1) -> registers (6 VMEM ops, issued FIRST)
    bf16x8 wf0[3], wf1[3];
#pragma unroll
    for (int i = 0; i < 3; ++i)
      wf0[i] = *reinterpret_cast<const bf16x8*>(wb + i * 16384 + (2 * t) * 512);
#pragma unroll
    for (int i = 0; i < 3; ++i)
      wf1[i] = *reinterpret_cast<const bf16x8*>(wb + i * 16384 + (2 * t + 1) * 512);

    if (t + 2 < 16) xstage(t + 2, xb_fut);

    // k-step s=0: MFMA's implicit wait on wf0 (vmcnt~7) transitively drains
    // x(t+1); xstage(t+2) stays in flight.
#pragma unroll
    for (int rt = 0; rt < 2; ++rt) {
      float4 lo = *reinterpret_cast<const float4*>(lds + xb_cur + xoffs[rt][0][0]);
      float4 hi = *reinterpret_cast<const float4*>(lds + xb_cur + xoffs[rt][0][1]);
      bf16x8 a = cvt8p(lo, hi);
#pragma unroll
      for (int i = 0; i < 3; ++i) acc[i][rt] = MFMA(a, wf0[i], acc[i][rt]);
    }
    // k-step s=1 (waits wf1, vmcnt~4)
#pragma unroll
    for (int rt = 0; rt < 2; ++rt) {
      float4 lo = *reinterpret_cast<const float4*>(lds + xb_cur + xoffs[rt][1][0]);
      float4 hi = *reinterpret_cast<const float4*>(lds + xb_cur + xoffs[rt][1][1]);
      bf16x8 a = cvt8p(lo, hi);
#pragma unroll
      for (int i = 0; i < 3; ++i) acc[i][rt] = MFMA(a, wf1[i], acc[i][rt]);
    }

    // raw barrier: no implicit vmcnt(0) drain; x(t+2) stays in flight.
    asm volatile("" ::: "memory");
    __builtin_amdgcn_s_barrier();
    asm volatile("" ::: "memory");
    int tmp = xb_cur; xb_cur = xb_nxt; xb_nxt = xb_fut; xb_fut = tmp;
  }

  // ---- epilogue: fragment-tiled stores (tile = blockIdx.x) ----
  const size_t tile = blockIdx.x;
#pragma unroll
  for (int i = 0; i < 3; ++i) {
    const int u = wid * 3 + i;
    const int m = u >> 3, nt = u & 7;
    const int gprime = ((nt & 1) << 1) + (c >> 3);  // col-group (l'>>4)
    const int e = c & 7;
    if (m == 0) {
      // j = rt*4 + (nt>>1); l' = gprime*16 + (4g+rr)
#pragma unroll
      for (int rt = 0; rt < 2; ++rt)
#pragma unroll
        for (int rr = 0; rr < 4; ++rr)
          Qf[(tile * 8 + rt * 4 + (nt >> 1)) * 512 +
             (gprime * 16 + 4 * g + rr) * 8 + e] = (__bf16)acc[i][rt][rr];
    } else if (m == 1) {
      // rho = rt*16+4g+rr: hi = g&1; c'' = ((2rt+(g>>1))<<2)|rr
#pragma unroll
      for (int rt = 0; rt < 2; ++rt)
#pragma unroll
        for (int rr = 0; rr < 4; ++rr)
          Kf[(tile * 8 + 2 * (nt >> 1) + (g & 1)) * 512 +
             (gprime * 16 + (((2 * rt + (g >> 1)) << 2) | rr)) * 8 + e] =
              (__bf16)acc[i][rt][rr];
    } else {
      // j = nt; l' = (2rt+(g>>1))*16 + c; e = 4(g&1)+rr (contiguous in rr)
#pragma unroll
      for (int rt = 0; rt < 2; ++rt) {
        bf16x4 v4;
#pragma unroll
        for (int rr = 0; rr < 4; ++rr) v4[rr] = (__bf16)acc[i][rt][rr];
        *reinterpret_cast<bf16x4*>(
            Vf + (tile * 8 + nt) * 512 +
            ((2 * rt + (g >> 1)) * 16 + c) * 8 + 4 * (g & 1)) = v4;
      }
    }
  }
}

// ---------------------------------------------------------------------------
// Kernel 3: causal flash attention. 4 waves/block; each wave owns the FULL
// 32 q-rows (acc[2][8]) with 4-way kt split. All Q/K/V global loads are
// fragment-tiled: base + chunk*512 + l*8 -> perfectly coalesced 1KB blocks.
// S^T = mfma(K_perm, Q^T); P per-lane IS the PV B-fragment. Per-lane softmax
// gate (__all), lrun per-lane partial reduced once at wave end. exp2 domain.
// ---------------------------------------------------------------------------
__global__ __launch_bounds__(256, 2) void attn_kernel(
    const __bf16* __restrict__ Qf, const __bf16* __restrict__ Kf,
    const __bf16* __restrict__ Vf, float* __restrict__ out) {
  __shared__ float sm[4][32];
  __shared__ float sl[4][32];
  __shared__ float bufA[32][132];
  __shared__ float bufB[32][132];

  const int tid = threadIdx.x;
  const int wid = tid >> 6;
  const int l   = tid & 63;
  const int c   = l & 15;
  const int g   = l >> 4;
  const int bid = blockIdx.x;
  const int b   = (bid & 7) >> 1;                    // XCD-affine batch
  const int j   = ((bid >> 3) << 1) | (bid & 1);     // 0..127
  const int qt  = (j < 64) ? (127 - j) : (j - 64);   // big tiles dispatched first
  const int qb  = qt * 32;

  bf16x8 qf[2][4];
  {
    const __bf16* Qt = Qf + (size_t)(b * 128 + qt) * 4096 + l * 8;
#pragma unroll
    for (int rt = 0; rt < 2; ++rt)
#pragma unroll
      for (int cs = 0; cs < 4; ++cs)
        qf[rt][cs] = *reinterpret_cast<const bf16x8*>(Qt + (rt * 4 + cs) * 512);
  }

  f32x4 acc[2][8];
#pragma unroll
  for (int i = 0; i < 2; ++i)
#pragma unroll
    for (int d = 0; d < 8; ++d) acc[i][d] = 0.f;
  float mrun[2] = {-INFINITY, -INFINITY};
  float lrun[2] = {0.f, 0.f};   // PER-LANE partial sums (reduced at wave end)

  if (wid <= qt) {
    const __bf16* Kb8 = Kf + (size_t)b * 128 * 4096 + l * 8;
    const __bf16* Vb8 = Vf + (size_t)b * 128 * 4096 + l * 8;
    bf16x8 kreg[8];
    auto kload = [&](int kt) {
      const __bf16* kb = Kb8 + (size_t)kt * 4096;
#pragma unroll
      for (int jj = 0; jj < 8; ++jj)
        kreg[jj] = *reinterpret_cast<const bf16x8*>(kb + jj * 512);
    };
    kload(wid);

    for (int kt = wid; kt <= qt; kt += 4) {
      f32x4 s00 = 0.f, s01 = 0.f, s10 = 0.f, s11 = 0.f;
      __builtin_amdgcn_s_setprio(1);
#pragma unroll
      for (int cs = 0; cs < 4; ++cs) {
        s00 = MFMA(kreg[2 * cs], qf[0][cs], s00);
        s01 = MFMA(kreg[2 * cs + 1], qf[0][cs], s01);
        s10 = MFMA(kreg[2 * cs], qf[1][cs], s10);
        s11 = MFMA(kreg[2 * cs + 1], qf[1][cs], s11);
      }
      __builtin_amdgcn_s_setprio(0);

      bf16x8 vf[8];
      {
        const __bf16* vb = Vb8 + (size_t)kt * 4096;
#pragma unroll
        for (int db = 0; db < 8; ++db)
          vf[db] = *reinterpret_cast<const bf16x8*>(vb + db * 512);
      }

      if (kt + 4 <= qt) kload(kt + 4);        // prefetch next K tile

      const bool maskt = (kt == qt);           // only the diagonal tile
      bf16x8 pb[2];
#pragma unroll
      for (int rt = 0; rt < 2; ++rt) {
        float p[8];
        const f32x4 sa = rt ? s10 : s00;
        const f32x4 sb = rt ? s11 : s01;
#pragma unroll
        for (int rr = 0; rr < 4; ++rr) { p[rr] = sa[rr]; p[4 + rr] = sb[rr]; }
        if (maskt) {
          const int lim = rt * 16 + c;
#pragma unroll
          for (int jj = 0; jj < 8; ++jj)
            if (8 * g + jj > lim) p[jj] = -INFINITY;
        }
        // per-lane max only (no cross-lane on the common path)
        float t0 = fmaxf(fmaxf(p[0], p[1]), p[2]);
        float t1 = fmaxf(fmaxf(p[3], p[4]), p[5]);
        float t2 = fmaxf(fmaxf(p[6], p[7]), t0);
        float tmax = fmaxf(t1, t2);

        if (!__all(tmax <= mrun[rt] + 11.5415603f)) {   // rare: defer-max fired
          float cmax = fmaxf(tmax, __shfl_xor(tmax, 16));
          cmax = fmaxf(cmax, __shfl_xor(cmax, 32));     // column max (over g)
          float mnew = fmaxf(mrun[rt], cmax);
          float al   = fexp2(mrun[rt] - mnew);
          mrun[rt] = mnew;
          lrun[rt] *= al;
#pragma unroll
          for (int db = 0; db < 8; ++db) acc[rt][db] *= al;
        }
        const float mc = mrun[rt];
#pragma unroll
        for (int jj = 0; jj < 8; ++jj) p[jj] = fexp2(p[jj] - mc);
        lrun[rt] += ((p[0] + p[1]) + (p[2] + p[3])) + ((p[4] + p[5]) + (p[6] + p[7]));
#pragma unroll
        for (int jj = 0; jj < 8; ++jj) pb[rt][jj] = (__bf16)p[jj];
      }

      __builtin_amdgcn_s_setprio(1);
#pragma unroll
      for (int db = 0; db < 8; ++db) {
        acc[0][db] = MFMA(vf[db], pb[0], acc[0][db]);
        acc[1][db] = MFMA(vf[db], pb[1], acc[1][db]);
      }
      __builtin_amdgcn_s_setprio(0);
    }
  }

  // wave-end: reduce per-lane l partials across the 4 g-lanes of each column
#pragma unroll
  for (int rt = 0; rt < 2; ++rt) {
    lrun[rt] += __shfl_xor(lrun[rt], 16);
    lrun[rt] += __shfl_xor(lrun[rt], 32);
  }

  // ---- combine the 4 waves' partial (m, l, O) ----
  if (g == 0) {
    sm[wid][c] = mrun[0]; sm[wid][16 + c] = mrun[1];
    sl[wid][c] = lrun[0]; sl[wid][16 + c] = lrun[1];
  }
  __syncthreads();

  float linv[2];
#pragma unroll
  for (int rt = 0; rt < 2; ++rt) {
    const int q = rt * 16 + c;
    float ms = fmaxf(fmaxf(sm[0][q], sm[1][q]), fmaxf(sm[2][q], sm[3][q]));
    float ls = fexp2(sm[0][q] - ms) * sl[0][q] + fexp2(sm[1][q] - ms) * sl[1][q]
             + fexp2(sm[2][q] - ms) * sl[2][q] + fexp2(sm[3][q] - ms) * sl[3][q];
    float al = fexp2(mrun[rt] - ms);
#pragma unroll
    for (int db = 0; db < 8; ++db) acc[rt][db] *= al;
    linv[rt] = 1.0f / ls;
  }

  auto store_buf = [&](float(*buf)[132]) {
#pragma unroll
    for (int rt = 0; rt < 2; ++rt)
#pragma unroll
      for (int db = 0; db < 8; ++db)
        *reinterpret_cast<f32x4*>(&buf[rt * 16 + c][db * 16 + 4 * g]) = acc[rt][db];
  };
  auto add_buf = [&](float(*buf)[132]) {
#pragma unroll
    for (int rt = 0; rt < 2; ++rt)
#pragma unroll
      for (int db = 0; db < 8; ++db)
        acc[rt][db] += *reinterpret_cast<const f32x4*>(&buf[rt * 16 + c][db * 16 + 4 * g]);
  };

  if (wid == 2) store_buf(bufA);
  if (wid == 3) store_buf(bufB);
  __syncthreads();
  if (wid == 0) add_buf(bufA);
  if (wid == 1) add_buf(bufB);
  __syncthreads();
  if (wid == 1) store_buf(bufA);
  __syncthreads();
  if (wid == 0) {
    add_buf(bufA);
    float* op = out + ((size_t)b * T_ + qb) * HS_;
#pragma unroll
    for (int rt = 0; rt < 2; ++rt)
#pragma unroll
      for (int db = 0; db < 8; ++db) {
        f32x4 v = acc[rt][db] * linv[rt];
        *reinterpret_cast<f32x4*>(op + (size_t)(rt * 16 + c) * HS_ + db * 16 + 4 * g) = v;
      }
  }
}

// ---------------------------------------------------------------------------
extern "C" void kernel_launch(void* const* d_in, const int* in_sizes, int n_in,
                              void* d_out, int out_size, void* d_ws, size_t ws_size,
                              hipStream_t stream) {
  const float* x  = (const float*)d_in[0];
  const float* Wk = (const float*)d_in[1];
  const float* Wq = (const float*)d_in[2];
  const float* Wv = (const float*)d_in[3];
  float* out = (float*)d_out;

  char* ws = (char*)d_ws;
  __bf16* Wf = (__bf16*)ws;                              // 768 KiB (fragment-tiled)
  __bf16* Qf = (__bf16*)(ws + 786432);                   // 4 MiB (fragment-tiled)
  __bf16* Kf = (__bf16*)(ws + 786432 + 4194304);         // 4 MiB (fragment-tiled)
  __bf16* Vf = (__bf16*)(ws + 786432 + 8388608);         // 4 MiB (fragment-tiled)

  prep_w_kernel<<<48, 256, 0, stream>>>(Wk, Wq, Wv, Wf);
  proj_kernel<<<512, 512, 0, stream>>>(x, Wf, Qf, Kf, Vf);
  attn_kernel<<<512, 256, 0, stream>>>(Qf, Kf, Vf, out);
}